// Round 4
// baseline (263.000 us; speedup 1.0000x reference)
//
#include <hip/hip_runtime.h>

// Loss = L1*sl1(1,iou) + L2*sl1(t[:4],p[:4]) + L3*sl1(t[12],p[12]) + 0.5*L4*sl1(t[4:12],p[4:12])
// shapes: (B=256, N=8192, F=13) fp32. B*N = 2^21 rows.
//
// Round-2/3 post-mortem: global_load_lds staging caps at ~1.3 TB/s HBM
// regardless of pipeline schedule (r0 barrier-drained == r2 counted-vmcnt,
// both 83 us) => LDS-DMA return path is the throughput cap. r3's reg-staging
// test was contaminated: asm "memory" clobbers pinned the staging structs in
// scratch (VGPR=72, WRITE_SIZE=119 MB of spill traffic) — yet even
// scratch-thrashing moved 258 MB @ 2.77 TB/s through the normal VMEM path,
// proving VMEM > LDS-DMA.
//
// This version: NO LDS AT ALL. Each thread owns 4 consecutive rows =
// 208 B = 13 x float4, 16-B aligned (208 = 13*16). 13 aligned
// global_load_dwordx4 per tensor, rows unpacked with fully static float4
// component selection (no runtime indexing, no asm, no memory clobbers —
// nothing can be demoted to scratch). L1 sees 4x read amplification
// (4 x 16 B visits per 64 B line) ~ 22 us at L1 rate, under the ~35 us
// HBM/L3 bound => stays memory-bound on the fast path.
//
// 1024 blocks x 256 threads, 2 quads/thread, linear streaming.

#define NQUAD  524288           // (B*N)/4 quad-rows
#define NBLK   1024
#define NTHR   (NBLK * 256)     // 262144 threads
#define QPT    (NQUAD / NTHR)   // 2 quads per thread

// Static float4 component select — all args compile-time constants.
#define GETC(v, c) ((c) == 0 ? (v).x : (c) == 1 ? (v).y : (c) == 2 ? (v).z : (v).w)
#define GET(arr, idx) GETC(arr[(idx) >> 2], (idx) & 3)

__device__ __forceinline__ float sl1(float d) {
    d = fabsf(d);
    return d < 1.0f ? 0.5f * d * d : d - 0.5f;
}

// One quad (4 rows) from 13+13 float4s held in registers.
__device__ __forceinline__ float quad_loss(const float4* a, const float4* b) {
    float acc = 0.0f;
#pragma unroll
    for (int r = 0; r < 4; ++r) {
        float t[13], p[13];
#pragma unroll
        for (int f = 0; f < 13; ++f) {
            const int idx = r * 13 + f;        // compile-time after unroll
            t[f] = GET(a, idx);
            p[f] = GET(b, idx);
        }

        float s2 = sl1(t[0] - p[0]) + sl1(t[1] - p[1]) +
                   sl1(t[2] - p[2]) + sl1(t[3] - p[3]);

        float s4 = 0.0f;
#pragma unroll
        for (int f = 4; f < 12; ++f) s4 += sl1(t[f] - p[f]);

        float s3 = sl1(t[12] - p[12]);

        float xx1 = fmaxf(t[0], p[0]);
        float yy1 = fmaxf(t[1], p[1]);
        float xx2 = fminf(t[2], p[2]);
        float yy2 = fminf(t[3], p[3]);
        float w  = fmaxf(xx2 - xx1, 0.0f);
        float h  = fmaxf(yy2 - yy1, 0.0f);
        float inter = w * h;
        float a1 = (t[2] - t[0]) * (t[3] - t[1]);
        float a2 = (p[2] - p[0]) * (p[3] - p[1]);
        float iou = inter / (a1 + a2 - inter + 1e-7f);
        float s1 = sl1(1.0f - iou);

        // Exact power-of-two mean weights: B*N = 2^21.
        constexpr float W1 = 1.0f / 2097152.0f;    // 1/(B*N)
        constexpr float W2 = 1.0f / 8388608.0f;    // 1/(B*N*4)
        constexpr float W3 = 1.0f / 2097152.0f;    // 1/(B*N)
        constexpr float W4 = 1.0f / 33554432.0f;   // 0.5/(B*N*8)
        acc += W1 * s1 + W2 * s2 + W3 * s3 + W4 * s4;
    }
    return acc;
}

__global__ __launch_bounds__(256) void loss_stage1(const float* __restrict__ T,
                                                   const float* __restrict__ P,
                                                   float* __restrict__ partial) {
    __shared__ float wred[4];
    const int tid  = threadIdx.x;
    const int gtid = blockIdx.x * 256 + tid;

    float acc = 0.0f;
#pragma unroll
    for (int it = 0; it < QPT; ++it) {
        const long long q = gtid + (long long)it * NTHR;
        const float4* tq = (const float4*)(T + q * 52);   // 208 B, 16-B aligned
        const float4* pq = (const float4*)(P + q * 52);

        float4 a[13], b[13];
#pragma unroll
        for (int k = 0; k < 13; ++k) { a[k] = tq[k]; b[k] = pq[k]; }

        acc += quad_loss(a, b);
    }

    // Block reduction: wave64 shuffle -> 4-wave LDS -> one partial per block.
#pragma unroll
    for (int off = 32; off > 0; off >>= 1)
        acc += __shfl_down(acc, off, 64);
    if ((tid & 63) == 0) wred[tid >> 6] = acc;
    __syncthreads();
    if (tid == 0)
        partial[blockIdx.x] = wred[0] + wred[1] + wred[2] + wred[3];
}

__global__ __launch_bounds__(256) void loss_stage2(const float* __restrict__ partial,
                                                   float* __restrict__ out) {
    __shared__ float wred[4];
    const int tid = threadIdx.x;
    float a = 0.0f;
    for (int i = tid; i < NBLK; i += 256) a += partial[i];
#pragma unroll
    for (int off = 32; off > 0; off >>= 1)
        a += __shfl_down(a, off, 64);
    if ((tid & 63) == 0) wred[tid >> 6] = a;
    __syncthreads();
    if (tid == 0) out[0] = wred[0] + wred[1] + wred[2] + wred[3];
}

extern "C" void kernel_launch(void* const* d_in, const int* in_sizes, int n_in,
                              void* d_out, int out_size, void* d_ws, size_t ws_size,
                              hipStream_t stream) {
    const float* targets = (const float*)d_in[0];
    const float* preds   = (const float*)d_in[1];
    float* out     = (float*)d_out;
    float* partial = (float*)d_ws;   // NBLK floats of scratch

    loss_stage1<<<NBLK, 256, 0, stream>>>(targets, preds, partial);
    loss_stage2<<<1, 256, 0, stream>>>(partial, out);
}

// Round 6
// 228.965 us; speedup vs baseline: 1.1486x; 1.1486x over previous
//
#include <hip/hip_runtime.h>

// Loss = L1*sl1(1,iou) + L2*sl1(t[:4],p[:4]) + L3*sl1(t[12],p[12]) + 0.5*L4*sl1(t[4:12],p[4:12])
// shapes: (B=256, N=8192, F=13) fp32. B*N = 2^21 rows. 218 MB total input.
//
// History: r0/r2 global_load_lds staging caps at 83 us (~2.6 TB/s eff) at any
// pipeline depth => LDS-DMA return-path throughput cap. r3 reg-staging was
// poisoned by asm "memory" clobbers (structs demoted to scratch, 119 MB spill
// writes) — but proved plain VMEM moves 258 MB @ 2.77 TB/s even while
// thrashing scratch. r4 no-LDS direct float4 was defeated by the register
// allocator (VGPR=36, loads serialized, FETCH 248 MB, 115 us latency-bound).
// r5 = this same design; the container failed before running it (no infra
// diagnostics; no in-kernel cause identified — 53.3 KB LDS, uniform barriers,
// in-bounds addresses). Resubmitting with lambdas flattened to plain code.
//
// Design: r0's chunk/transpose shape with PLAIN VMEM staging. Per 256-row
// chunk each thread stages 26 dwords (3x dwordx4 + 1x dword per tensor) into
// named registers, computes the current chunk from LDS, then ds_writes the
// staged regs into the other buffer (T14 issue-early/write-late). One barrier
// per iteration; 3 blocks/CU (53.3 KB LDS) x 8 staged loads x 256 thr
// ~ 80 KB/CU in flight covers HBM latency with ~3x slack. Linear LDS layout:
// b128 writes conflict-free; row reads (13-dword lane stride) are a free
// 2-way bank alias (m136). No global_load_lds, no inline asm, no clobbers.

#define NCHUNK 8192             // (B*N)/256 chunks of 256 rows
#define NBLK   768              // 3 blocks/CU * 256 CU; grid-stride over chunks
#define CH_F4  832              // float4s per tensor-chunk (256 rows * 52 B / 16)
#define CH_DW  3328             // dwords per tensor-chunk

__device__ __forceinline__ float sl1(float d) {
    d = fabsf(d);
    return d < 1.0f ? 0.5f * d * d : d - 0.5f;
}

__global__ __launch_bounds__(256) void loss_stage1(const float* __restrict__ T,
                                                   const float* __restrict__ P,
                                                   float* __restrict__ partial) {
    __shared__ __align__(16) float lt[2][CH_DW];   // 26,624 B
    __shared__ __align__(16) float lp[2][CH_DW];   // 26,624 B
    __shared__ float wred[4];

    const int tid = threadIdx.x;

    // Staging registers: 26 dwords/thread — named, fully static.
    float4 rt0, rt1, rt2, rp0, rp1, rp2;
    float  rtt, rpt;

    // ---- Prologue: load chunk blockIdx.x, write into buffer 0 ----
    int c = blockIdx.x;
    {
        const float4* tb = (const float4*)T + (long long)c * CH_F4;
        const float4* pb = (const float4*)P + (long long)c * CH_F4;
        rt0 = tb[tid]; rt1 = tb[tid + 256]; rt2 = tb[tid + 512];
        rp0 = pb[tid]; rp1 = pb[tid + 256]; rp2 = pb[tid + 512];
        rtt = ((const float*)(tb + 768))[tid];
        rpt = ((const float*)(pb + 768))[tid];

        float4* dt = (float4*)lt[0];
        float4* dp = (float4*)lp[0];
        dt[tid] = rt0; dt[tid + 256] = rt1; dt[tid + 512] = rt2;
        dp[tid] = rp0; dp[tid + 256] = rp1; dp[tid + 512] = rp2;
        lt[0][3072 + tid] = rtt;
        lp[0][3072 + tid] = rpt;
    }
    __syncthreads();

    int cur = 0;
    float acc = 0.0f;

    while (c < NCHUNK) {
        const int cn = c + NBLK;
        const bool more = (cn < NCHUNK);

        // Issue-early: next chunk's 8 loads; latency hides under compute below.
        if (more) {
            const float4* tb = (const float4*)T + (long long)cn * CH_F4;
            const float4* pb = (const float4*)P + (long long)cn * CH_F4;
            rt0 = tb[tid]; rt1 = tb[tid + 256]; rt2 = tb[tid + 512];
            rp0 = pb[tid]; rp1 = pb[tid + 256]; rp2 = pb[tid + 512];
            rtt = ((const float*)(tb + 768))[tid];
            rpt = ((const float*)(pb + 768))[tid];
        }

        // Compute row `tid` of the current chunk from LDS.
        const float* t = lt[cur];
        const float* p = lp[cur];
        const int rb = tid * 13;

        float t0 = t[rb + 0], t1 = t[rb + 1], t2 = t[rb + 2], t3 = t[rb + 3];
        float p0 = p[rb + 0], p1 = p[rb + 1], p2 = p[rb + 2], p3 = p[rb + 3];

        float s2 = sl1(t0 - p0) + sl1(t1 - p1) + sl1(t2 - p2) + sl1(t3 - p3);

        float s4 = 0.0f;
#pragma unroll
        for (int f = 4; f < 12; ++f) s4 += sl1(t[rb + f] - p[rb + f]);

        float s3 = sl1(t[rb + 12] - p[rb + 12]);

        float xx1 = fmaxf(t0, p0);
        float yy1 = fmaxf(t1, p1);
        float xx2 = fminf(t2, p2);
        float yy2 = fminf(t3, p3);
        float w  = fmaxf(xx2 - xx1, 0.0f);
        float h  = fmaxf(yy2 - yy1, 0.0f);
        float inter = w * h;
        float a1 = (t2 - t0) * (t3 - t1);
        float a2 = (p2 - p0) * (p3 - p1);
        float iou = inter / (a1 + a2 - inter + 1e-7f);
        float s1 = sl1(1.0f - iou);

        // Exact power-of-two mean weights: B*N = 2^21.
        constexpr float W1 = 1.0f / 2097152.0f;    // 1/(B*N)
        constexpr float W2 = 1.0f / 8388608.0f;    // 1/(B*N*4)
        constexpr float W3 = 1.0f / 2097152.0f;    // 1/(B*N)
        constexpr float W4 = 1.0f / 33554432.0f;   // 0.5/(B*N*8)
        acc += W1 * s1 + W2 * s2 + W3 * s3 + W4 * s4;

        // Write-late: staged regs -> other buffer. The compiler's vmcnt waits
        // land here, behind the compute; co-resident blocks cover the rest.
        if (more) {
            const int nb = cur ^ 1;
            float4* dt = (float4*)lt[nb];
            float4* dp = (float4*)lp[nb];
            dt[tid] = rt0; dt[tid + 256] = rt1; dt[tid + 512] = rt2;
            dp[tid] = rp0; dp[tid + 256] = rp1; dp[tid + 512] = rp2;
            lt[nb][3072 + tid] = rtt;
            lp[nb][3072 + tid] = rpt;
        }
        __syncthreads();
        cur ^= 1;
        c = cn;
    }

    // Block reduction: wave64 shuffle -> 4-wave LDS -> one partial per block.
#pragma unroll
    for (int off = 32; off > 0; off >>= 1)
        acc += __shfl_down(acc, off, 64);
    if ((tid & 63) == 0) wred[tid >> 6] = acc;
    __syncthreads();
    if (tid == 0)
        partial[blockIdx.x] = wred[0] + wred[1] + wred[2] + wred[3];
}

__global__ __launch_bounds__(256) void loss_stage2(const float* __restrict__ partial,
                                                   float* __restrict__ out) {
    __shared__ float wred[4];
    const int tid = threadIdx.x;
    float a = 0.0f;
    for (int i = tid; i < NBLK; i += 256) a += partial[i];
#pragma unroll
    for (int off = 32; off > 0; off >>= 1)
        a += __shfl_down(a, off, 64);
    if ((tid & 63) == 0) wred[tid >> 6] = a;
    __syncthreads();
    if (tid == 0) out[0] = wred[0] + wred[1] + wred[2] + wred[3];
}

extern "C" void kernel_launch(void* const* d_in, const int* in_sizes, int n_in,
                              void* d_out, int out_size, void* d_ws, size_t ws_size,
                              hipStream_t stream) {
    const float* targets = (const float*)d_in[0];
    const float* preds   = (const float*)d_in[1];
    float* out     = (float*)d_out;
    float* partial = (float*)d_ws;   // NBLK floats of scratch

    loss_stage1<<<NBLK, 256, 0, stream>>>(targets, preds, partial);
    loss_stage2<<<1, 256, 0, stream>>>(partial, out);
}